// Round 12
// baseline (1229.904 us; speedup 1.0000x reference)
//
#include <hip/hip_runtime.h>
#include <math.h>

typedef __bf16 bf16_t;
typedef __bf16 bf16x8 __attribute__((ext_vector_type(8)));
typedef float f32x4 __attribute__((ext_vector_type(4)));

__device__ __forceinline__ void gload_lds16(const void* g, void* l) {
    __builtin_amdgcn_global_load_lds(
        (const __attribute__((address_space(1))) void*)g,
        (__attribute__((address_space(3))) void*)l, 16, 0, 0);
}

// ---------------- f32 -> bf16 convert ----------------
__global__ void k_f2b(const float* __restrict__ in, bf16_t* __restrict__ out, int n8) {
    int idx = blockIdx.x * 256 + threadIdx.x;
    if (idx >= n8) return;
    const float* p = in + (size_t)idx * 8;
    bf16x8 r;
#pragma unroll
    for (int j = 0; j < 8; j++) r[j] = (bf16_t)p[j];
    *(bf16x8*)(out + (size_t)idx * 8) = r;
}

// strided-dest variant (per-layer interleave into wqkv)
__global__ void k_f2b_s(const float* __restrict__ in, bf16_t* __restrict__ out,
                        int seg8, int dstride8) {
    int idx = blockIdx.x * 256 + threadIdx.x;
    int seg = idx / seg8, rem = idx - seg * seg8;
    const float* p = in + (size_t)idx * 8;
    bf16x8 r;
#pragma unroll
    for (int j = 0; j < 8; j++) r[j] = (bf16_t)p[j];
    *(bf16x8*)(out + ((size_t)seg * dstride8 + rem) * 8) = r;
}

// ---------------- sinusoidal time embedding ----------------
__global__ void k_time_embed(const float* __restrict__ time, float* __restrict__ temb0) {
    int b = blockIdx.x;
    int j = threadIdx.x;              // 0..255
    float f = __expf((float)j * -0.036118981458730134f); // -ln(10000)/255
    float e = time[b] * f;
    temb0[(size_t)b * 512 + j] = sinf(e);
    temb0[(size_t)b * 512 + 256 + j] = cosf(e);
}

// ---------------- LayerNorm (or plain cast) -> bf16, rows of 512 ----------------
// IN32: input fp32, else bf16
template<bool DO_NORM, bool IN32>
__global__ void k_ln(const void* __restrict__ xp, const float* __restrict__ g,
                     const float* __restrict__ b, bf16_t* __restrict__ out) {
    int row = blockIdx.x * 4 + (threadIdx.x >> 6);
    int lane = threadIdx.x & 63;
    float vals[8];
    if (IN32) {
        const float* xr = (const float*)xp + (size_t)row * 512 + lane * 8;
        float4 v0 = *(const float4*)xr;
        float4 v1 = *(const float4*)(xr + 4);
        vals[0] = v0.x; vals[1] = v0.y; vals[2] = v0.z; vals[3] = v0.w;
        vals[4] = v1.x; vals[5] = v1.y; vals[6] = v1.z; vals[7] = v1.w;
    } else {
        bf16x8 xv = *(const bf16x8*)((const bf16_t*)xp + (size_t)row * 512 + lane * 8);
#pragma unroll
        for (int j = 0; j < 8; j++) vals[j] = (float)xv[j];
    }
    bf16x8 r;
    if (DO_NORM) {
        float s = 0.f, sq = 0.f;
#pragma unroll
        for (int j = 0; j < 8; j++) { s += vals[j]; sq += vals[j] * vals[j]; }
#pragma unroll
        for (int m = 1; m < 64; m <<= 1) { s += __shfl_xor(s, m, 64); sq += __shfl_xor(sq, m, 64); }
        float mean = s * (1.0f / 512.0f);
        float var = sq * (1.0f / 512.0f) - mean * mean;
        float rstd = rsqrtf(var + 1e-5f);
        float4 g0 = *(const float4*)(g + lane * 8);
        float4 g1 = *(const float4*)(g + lane * 8 + 4);
        float4 b0 = *(const float4*)(b + lane * 8);
        float4 b1 = *(const float4*)(b + lane * 8 + 4);
        float gs[8] = {g0.x, g0.y, g0.z, g0.w, g1.x, g1.y, g1.z, g1.w};
        float bs[8] = {b0.x, b0.y, b0.z, b0.w, b1.x, b1.y, b1.z, b1.w};
#pragma unroll
        for (int j = 0; j < 8; j++) r[j] = (bf16_t)((vals[j] - mean) * rstd * gs[j] + bs[j]);
    } else {
#pragma unroll
        for (int j = 0; j < 8; j++) r[j] = (bf16_t)vals[j];
    }
    *(bf16x8*)(out + (size_t)row * 512 + lane * 8) = r;
}

// ---------------- head prep: LN(x[:, -1]) -> relu -> f32 z[32,512] ----------------
__global__ void k_head_prep(const bf16_t* __restrict__ x, const float* __restrict__ g,
                            const float* __restrict__ b, float* __restrict__ z) {
    int row = blockIdx.x * 4 + (threadIdx.x >> 6); // 0..31
    int lane = threadIdx.x & 63;
    bf16x8 xv = *(const bf16x8*)(x + ((size_t)row * 512 + 511) * 512 + lane * 8);
    float vals[8];
#pragma unroll
    for (int j = 0; j < 8; j++) vals[j] = (float)xv[j];
    float s = 0.f, sq = 0.f;
#pragma unroll
    for (int j = 0; j < 8; j++) { s += vals[j]; sq += vals[j] * vals[j]; }
#pragma unroll
    for (int m = 1; m < 64; m <<= 1) { s += __shfl_xor(s, m, 64); sq += __shfl_xor(sq, m, 64); }
    float mean = s * (1.0f / 512.0f);
    float var = sq * (1.0f / 512.0f) - mean * mean;
    float rstd = rsqrtf(var + 1e-5f);
    float o[8];
#pragma unroll
    for (int j = 0; j < 8; j++) {
        float gv = g[lane * 8 + j], bv = b[lane * 8 + j];
        o[j] = fmaxf((vals[j] - mean) * rstd * gv + bv, 0.0f);
    }
    float* zr = z + (size_t)row * 512 + lane * 8;
    *(float4*)zr = make_float4(o[0], o[1], o[2], o[3]);
    *(float4*)(zr + 4) = make_float4(o[4], o[5], o[6], o[7]);
}

// ---------------- fp32 GEMM, M=32 (time MLP + head) ----------------
template<int ACT, int K, bool OUTB>  // ACT: 0 none, 1 gelu(exact), 2 silu
__global__ __launch_bounds__(256, 2)
void k_gemm_tm(const float* __restrict__ A, const float* __restrict__ W,
               const float* __restrict__ bias, void* __restrict__ outp, int N) {
    __shared__ float Asm[32][516];
    const int t = threadIdx.x;
    const int kq = t & 7, rw = (t >> 3) & 7, bh = t >> 6;
    const int n0 = blockIdx.x * 32;
    float acc[4][8] = {};
    for (int k0 = 0; k0 < K; k0 += 512) {
        __syncthreads();
#pragma unroll
        for (int i = 0; i < 16; i++) {
            int fid = t + i * 256;
            int row = fid >> 7, cc = (fid & 127) << 2;
            *(float4*)&Asm[row][cc] = *(const float4*)&A[(size_t)row * K + k0 + cc];
        }
        __syncthreads();
#pragma unroll 4
        for (int j = 0; j < 16; j++) {
            int kk = kq * 4 + j * 32;
            float4 w4[4];
#pragma unroll
            for (int r = 0; r < 4; r++)
                w4[r] = *(const float4*)&W[(size_t)(n0 + rw + r * 8) * K + k0 + kk];
#pragma unroll
            for (int b = 0; b < 8; b++) {
                float4 a4 = *(const float4*)&Asm[bh * 8 + b][kk];
#pragma unroll
                for (int r = 0; r < 4; r++)
                    acc[r][b] += a4.x * w4[r].x + a4.y * w4[r].y + a4.z * w4[r].z + a4.w * w4[r].w;
            }
        }
    }
#pragma unroll
    for (int m = 1; m < 8; m <<= 1)
#pragma unroll
        for (int r = 0; r < 4; r++)
#pragma unroll
            for (int b = 0; b < 8; b++)
                acc[r][b] += __shfl_xor(acc[r][b], m, 64);
    if (kq == 0) {
#pragma unroll
        for (int r = 0; r < 4; r++) {
            int n = n0 + rw + r * 8;
            float bv = bias[n];
#pragma unroll
            for (int b = 0; b < 8; b++) {
                float v = acc[r][b] + bv;
                if (ACT == 1) v = 0.5f * v * (1.0f + erff(v * 0.70710678118654752f));
                if (ACT == 2) v = v / (1.0f + __expf(-v));
                if (OUTB) ((bf16_t*)outp)[(size_t)(bh * 8 + b) * N + n] = (bf16_t)v;
                else      ((float*)outp)[(size_t)(bh * 8 + b) * N + n] = v;
            }
        }
    }
}

// ---------------- tm_t prefill with bias ----------------
__global__ void k_fill_tmt(const float* __restrict__ bt, float* __restrict__ tm_t) {
    int i = blockIdx.x * 256 + threadIdx.x;   // over 16384*32
    tm_t[i] = bt[i >> 5];
}

// ---------------- Wt GEMM: tm_t[16384,32] += Wt[16384,2048] @ t2s_b[32,2048]^T -----
__global__ __launch_bounds__(256, 4)
void k_gemm_wt(const float* __restrict__ Wt, const bf16_t* __restrict__ t2s_b,
               float* __restrict__ tm_t) {
    __shared__ __align__(16) bf16_t Abuf[64 * 64];
    __shared__ __align__(16) bf16_t Bbuf[32 * 64];
    const int tid = threadIdx.x;
    const int m0 = blockIdx.x * 64;
    const int k0 = blockIdx.y * 512;
    const int lane = tid & 63, wave = tid >> 6;
    const int arow = tid >> 2, aseg = tid & 3;
    const int brow = tid >> 3, bseg = tid & 7;
    const int aswz = (arow & 7) << 4;
    const char* Bg = (const char*)t2s_b + (size_t)brow * 4096 + ((bseg * 16) ^ ((brow & 7) << 4));
    char* BbL = (char*)Bbuf + tid * 16;
    const float* Ar0 = Wt + (size_t)(m0 + arow) * 2048 + k0 + aseg * 16;
    f32x4 acc[2] = {};
    for (int kk0 = 0; kk0 < 512; kk0 += 64) {
        float4 a4[4];
#pragma unroll
        for (int i = 0; i < 4; i++) a4[i] = *(const float4*)(Ar0 + kk0 + i * 4);
        __syncthreads();
        gload_lds16(Bg + (size_t)(k0 + kk0) * 2, BbL);
        bf16x8 c0, c1;
#pragma unroll
        for (int i = 0; i < 4; i++) {
            const float* af = (const float*)&a4[i];
#pragma unroll
            for (int j = 0; j < 4; j++) {
                if (i < 2) c0[i * 4 + j] = (bf16_t)af[j];
                else       c1[(i - 2) * 4 + j] = (bf16_t)af[j];
            }
        }
        int base = arow * 128 + aseg * 32;
        *(bf16x8*)((char*)Abuf + (base ^ aswz)) = c0;
        *(bf16x8*)((char*)Abuf + ((base + 16) ^ aswz)) = c1;
        __syncthreads();
#pragma unroll
        for (int kk = 0; kk < 2; kk++) {
            int ar = wave * 16 + (lane & 15);
            bf16x8 af = *(const bf16x8*)((const char*)Abuf + ar * 128 +
                        ((kk * 64 + (lane >> 4) * 16) ^ ((ar & 7) << 4)));
#pragma unroll
            for (int j = 0; j < 2; j++) {
                int br = j * 16 + (lane & 15);
                bf16x8 bfr = *(const bf16x8*)((const char*)Bbuf + br * 128 +
                             ((kk * 64 + (lane >> 4) * 16) ^ ((br & 7) << 4)));
                acc[j] = __builtin_amdgcn_mfma_f32_16x16x32_bf16(af, bfr, acc[j], 0, 0, 0);
            }
        }
    }
#pragma unroll
    for (int j = 0; j < 2; j++)
#pragma unroll
        for (int r = 0; r < 4; r++) {
            int mrow = m0 + wave * 16 + (lane >> 4) * 4 + r;
            atomicAdd(&tm_t[(size_t)mrow * 32 + j * 16 + (lane & 15)], acc[j][r]);
        }
}

// ---------------- wave-pipelined MFMA GEMM: NO barriers, wave-private LDS ------------
// Block = 4 waves (2M x 2N), each wave owns 64x64 out and PRIVATE dbuf LDS (2 x 8KB).
// Per K-step (BK=32): stage next tile (8 gload_lds) -> vmcnt(8) -> ds_read 8 frags ->
// 16 MFMA -> lgkmcnt(0). Waves free-run; CU interleaves their mem/LDS/MFMA phases.
enum { EPI_QKV = 0, EPI_RESID = 1, EPI_FILMGLU = 2 };

template<int EPI, int K, int NBY, bool RS32>
__global__ __launch_bounds__(256, 2)
void k_gemm_wp(const bf16_t* __restrict__ A, const bf16_t* __restrict__ W,
               const float* __restrict__ bias, const float* __restrict__ bias2,
               const float* __restrict__ bias3,
               void* __restrict__ out0, const void* __restrict__ rsp, void* __restrict__ out2,
               const float* __restrict__ tm) {
    __shared__ __align__(16) char lds_raw[4][2][8192];   // [wave][buf][A 4KB | B 4KB]
    const int tid = threadIdx.x;
    // XCD-bijective swizzle; A-panel-contiguous (by fast within wg)
    const int cpx = gridDim.x >> 3;
    const int wg = (blockIdx.x & 7) * cpx + (blockIdx.x >> 3);
    const int bx = wg / NBY;
    const int by = wg - bx * NBY;
    const int m0 = bx * 128;
    const int lane = tid & 63;
    const int wid = tid >> 6;
    const int wrM = (wid >> 1) * 64;
    const int wN  = wid & 1;
    const int wc  = wN * 64;

    // staging geometry: instr i covers 16 rows x 64B; lane -> row i*16+(lane>>2), slot lane&3
    const int srw  = lane >> 2;                                   // 0..15
    const int cswz = (((lane & 3) ^ (srw & 3)) << 4);             // pre-swizzled src 16B slot
    const char* Ag = (const char*)A;
    const char* Wg = (const char*)W;
    size_t arowoff[4], browoff[4];
#pragma unroll
    for (int i = 0; i < 4; i++) {
        arowoff[i] = (size_t)(m0 + wrM + i * 16 + srw) * (K * 2);
        int rb = wc + i * 16 + srw;      // block-local B row 0..127
        int grow;
        if (EPI == EPI_FILMGLU) {
            int half = (rb >> 5) & 1;
            grow = half * 1024 + by * 64 + (rb >> 6) * 32 + (rb & 31);
        } else {
            grow = by * 128 + rb;
        }
        browoff[i] = (size_t)grow * (K * 2);
    }

    auto stage = [&](int buf, int t) {   // 8 gload_lds, wave-private dest
        const int k0 = t * 64;           // bytes (BK=32)
        char* dst = lds_raw[wid][buf] + lane * 16;
#pragma unroll
        for (int i = 0; i < 4; i++)
            gload_lds16(Ag + arowoff[i] + k0 + cswz, dst + i * 1024);
#pragma unroll
        for (int i = 0; i < 4; i++)
            gload_lds16(Wg + browoff[i] + k0 + cswz, dst + 4096 + i * 1024);
    };

    f32x4 acc[4][4] = {};
    const int rdswz = (((lane >> 4) ^ (lane & 3)) << 4);   // slot = ks ^ (row&3)
    auto compute = [&](int buf) {
        const char* ra = lds_raw[wid][buf];
        const char* rb = ra + 4096;
        bf16x8 af[4], bf[4];
#pragma unroll
        for (int i = 0; i < 4; i++) {
            af[i] = *(const bf16x8*)(ra + (i * 16 + (lane & 15)) * 64 + rdswz);
            bf[i] = *(const bf16x8*)(rb + (i * 16 + (lane & 15)) * 64 + rdswz);
        }
#pragma unroll
        for (int i = 0; i < 4; i++)
#pragma unroll
            for (int j = 0; j < 4; j++)
                acc[i][j] = __builtin_amdgcn_mfma_f32_16x16x32_bf16(af[i], bf[j], acc[i][j], 0, 0, 0);
        // all ds_reads retired before any later gload_lds overwrites this buffer
        asm volatile("s_waitcnt lgkmcnt(0)" ::: "memory");
    };

    const int NT = K / 32;
    stage(0, 0);
    for (int t = 0; t < NT - 1; ++t) {
        stage((t + 1) & 1, t + 1);                           // next tile in flight
        asm volatile("s_waitcnt vmcnt(8)" ::: "memory");     // tile t landed
        compute(t & 1);
    }
    asm volatile("s_waitcnt vmcnt(0)" ::: "memory");
    compute((NT - 1) & 1);

    const int b = m0 >> 9;   // uniform per block
    if (EPI == EPI_QKV) {
        const int which = by >> 2;
        bf16_t* op = (bf16_t*)(which == 0 ? out0 : which == 1 ? (void*)rsp : out2);
        const float* bp = which == 0 ? bias : which == 1 ? bias2 : bias3;
#pragma unroll
        for (int i = 0; i < 4; i++) {
#pragma unroll
            for (int r = 0; r < 4; r++) {
                int s = (m0 + wrM + i * 16 + (lane >> 4) * 4 + r) & 511;
#pragma unroll
                for (int j = 0; j < 4; j++) {
                    int c = (by & 3) * 128 + wc + j * 16 + (lane & 15);
                    float v = acc[i][j][r] + bp[c];
                    int h = c >> 6, dh = c & 63;
                    op[(((size_t)b * 8 + h) * 512 + s) * 64 + dh] = (bf16_t)v;
                }
            }
        }
    } else if (EPI == EPI_RESID) {
        bf16_t* op = (bf16_t*)out0;
#pragma unroll
        for (int i = 0; i < 4; i++) {
#pragma unroll
            for (int r = 0; r < 4; r++) {
                int row = m0 + wrM + i * 16 + (lane >> 4) * 4 + r;
#pragma unroll
                for (int j = 0; j < 4; j++) {
                    int col = by * 128 + wc + j * 16 + (lane & 15);
                    size_t idx = (size_t)row * 512 + col;
                    float rsv = RS32 ? ((const float*)rsp)[idx] : (float)((const bf16_t*)rsp)[idx];
                    op[idx] = (bf16_t)(rsv + acc[i][j][r] + bias[col]);
                }
            }
        }
    } else { // EPI_FILMGLU; tm is tm_t layout [16384 cols][32 batches]
        bf16_t* op = (bf16_t*)out0;
#pragma unroll
        for (int i = 0; i < 4; i++) {
#pragma unroll
            for (int r = 0; r < 4; r++) {
                int row = m0 + wrM + i * 16 + (lane >> 4) * 4 + r;
#pragma unroll
                for (int jj = 0; jj < 2; jj++) {
                    int colA = by * 64 + wN * 32 + jj * 16 + (lane & 15);
                    float av = acc[i][jj][r] + bias[colA];
                    float gv = acc[i][jj + 2][r] + bias[1024 + colA];
                    float sa = tm[(size_t)colA * 32 + b];
                    float ha = tm[(size_t)(2048 + colA) * 32 + b];
                    float sg = tm[(size_t)(1024 + colA) * 32 + b];
                    float hg = tm[(size_t)(3072 + colA) * 32 + b];
                    av = av * (1.0f + sa) + ha;
                    gv = gv * (1.0f + sg) + hg;
                    op[(size_t)row * 1024 + colA] = (bf16_t)(av * fmaxf(gv, 0.0f));
                }
            }
        }
    }
}

// ---------------- fused flash attention, per (q-tile 64, b*h); XCD-chunked grid ------
__global__ __launch_bounds__(256, 2)
void k_attn(const bf16_t* __restrict__ q, const bf16_t* __restrict__ k,
            const bf16_t* __restrict__ v, bf16_t* __restrict__ o) {
    __shared__ bf16_t q_lds[64][72];
    __shared__ bf16_t k_lds[64][72];
    __shared__ bf16_t vt_lds[64 * 72];   // row d (stride 144B), cols s, XOR-swizzled
    __shared__ bf16_t p_lds[64][72];
    const int tid = threadIdx.x;
    const int lane = tid & 63;
    const int wave = tid >> 6;
    // XCD swizzle: 8 qt-blocks of the same (b,h) land on one XCD for K/V L2 reuse
    const int cpx = gridDim.x >> 3;                              // 256
    const int wg = ((int)blockIdx.x & 7) * cpx + ((int)blockIdx.x >> 3);
    const int bh = wg >> 3;      // 0..255
    const int qt = wg & 7;       // 0..7
    const bf16_t* qb = q + ((size_t)bh * 512 + qt * 64) * 64;
    const bf16_t* kb = k + (size_t)bh * 512 * 64;
    const bf16_t* vb = v + (size_t)bh * 512 * 64;
    const int sr = tid >> 2;          // 0..63
    const int sc = (tid & 3) * 16;    // 0,16,32,48
    { // stage Q once, folding in SCALE=0.125 (exact in bf16)
        bf16x8 a0 = *(const bf16x8*)(qb + sr * 64 + sc);
        bf16x8 a1 = *(const bf16x8*)(qb + sr * 64 + sc + 8);
        bf16x8 ra, rb;
#pragma unroll
        for (int j = 0; j < 8; j++) {
            ra[j] = (bf16_t)((float)a0[j] * 0.125f);
            rb[j] = (bf16_t)((float)a1[j] * 0.125f);
        }
        *(bf16x8*)&q_lds[sr][sc] = ra;
        *(bf16x8*)&q_lds[sr][sc + 8] = rb;
    }
    // prefetch regs for K/V tile 0
    bf16x8 kr0, kr1, vr0, vr1;
    {
        const bf16_t* ks = kb + (size_t)sr * 64 + sc;
        const bf16_t* vs = vb + (size_t)sr * 64 + sc;
        kr0 = *(const bf16x8*)ks; kr1 = *(const bf16x8*)(ks + 8);
        vr0 = *(const bf16x8*)vs; vr1 = *(const bf16x8*)(vs + 8);
    }
    float mrow[4], lrow[4];
    f32x4 oacc[4] = {};
#pragma unroll
    for (int r = 0; r < 4; r++) { mrow[r] = -1e30f; lrow[r] = 0.f; }
    const int swz0 = ((sc >> 3) & 7) << 4;
    const int swz1 = (((sc + 8) >> 3) & 7) << 4;
    for (int kt = 0; kt < 8; kt++) {
        __syncthreads();
        {
            *(bf16x8*)&k_lds[sr][sc] = kr0;
            *(bf16x8*)&k_lds[sr][sc + 8] = kr1;
            char* vbase = (char*)vt_lds;
            int so0 = (sr * 2) ^ swz0;
            int so1 = (sr * 2) ^ swz1;
#pragma unroll
            for (int j = 0; j < 8; j++) {
                *(bf16_t*)(vbase + (sc + j) * 144 + so0) = vr0[j];
                *(bf16_t*)(vbase + (sc + 8 + j) * 144 + so1) = vr1[j];
            }
        }
        __syncthreads();
        if (kt < 7) {
            const bf16_t* ks = kb + ((size_t)(kt + 1) * 64 + sr) * 64 + sc;
            const bf16_t* vs = vb + ((size_t)(kt + 1) * 64 + sr) * 64 + sc;
            kr0 = *(const bf16x8*)ks; kr1 = *(const bf16x8*)(ks + 8);
            vr0 = *(const bf16x8*)vs; vr1 = *(const bf16x8*)(vs + 8);
        }
        f32x4 sacc[4] = {};
#pragma unroll
        for (int kk = 0; kk < 2; kk++) {
            bf16x8 aq = *(const bf16x8*)&q_lds[wave * 16 + (lane & 15)][kk * 32 + (lane >> 4) * 8];
#pragma unroll
            for (int c = 0; c < 4; c++) {
                bf16x8 bk8 = *(const bf16x8*)&k_lds[c * 16 + (lane & 15)][kk * 32 + (lane >> 4) * 8];
                sacc[c] = __builtin_amdgcn_mfma_f32_16x16x32_bf16(aq, bk8, sacc[c], 0, 0, 0);
            }
        }
#pragma unroll
        for (int r = 0; r < 4; r++) {
            float mx = fmaxf(fmaxf(sacc[0][r], sacc[1][r]), fmaxf(sacc[2][r], sacc[3][r]));
#pragma unroll
            for (int m = 1; m < 16; m <<= 1) mx = fmaxf(mx, __shfl_xor(mx, m, 64));
            float newm = fmaxf(mrow[r], mx);
            float fsc = __expf(mrow[r] - newm);
            mrow[r] = newm;
            float p0 = __expf(sacc[0][r] - newm);
            float p1 = __expf(sacc[1][r] - newm);
            float p2 = __expf(sacc[2][r] - newm);
            float p3 = __expf(sacc[3][r] - newm);
            float ps = p0 + p1 + p2 + p3;
#pragma unroll
            for (int m = 1; m < 16; m <<= 1) ps += __shfl_xor(ps, m, 64);
            lrow[r] = lrow[r] * fsc + ps;
#pragma unroll
            for (int c = 0; c < 4; c++) oacc[c][r] *= fsc;
            int qrow = wave * 16 + (lane >> 4) * 4 + r;
            p_lds[qrow][(lane & 15)] = (bf16_t)p0;
            p_lds[qrow][16 + (lane & 15)] = (bf16_t)p1;
            p_lds[qrow][32 + (lane & 15)] = (bf16_t)p2;
            p_lds[qrow][48 + (lane & 15)] = (bf16_t)p3;
        }
        // p_lds rows are wave-local: no block barrier needed before PV
#pragma unroll
        for (int kk = 0; kk < 2; kk++) {
            bf16x8 ap = *(const bf16x8*)&p_lds[wave * 16 + (lane & 15)][kk * 32 + (lane >> 4) * 8];
#pragma unroll
            for (int c = 0; c < 4; c++) {
                int d0 = c * 16 + (lane & 15);
                int xo = ((d0 >> 3) & 7) << 4;
                bf16x8 bv8 = *(const bf16x8*)((const char*)vt_lds + d0 * 144 +
                              ((kk * 64 + (lane >> 4) * 16) ^ xo));
                oacc[c] = __builtin_amdgcn_mfma_f32_16x16x32_bf16(ap, bv8, oacc[c], 0, 0, 0);
            }
        }
    }
    const int b = bh >> 3, h = bh & 7;
#pragma unroll
    for (int r = 0; r < 4; r++) {
        int s = qt * 64 + wave * 16 + (lane >> 4) * 4 + r;
        float inv = 1.0f / lrow[r];
#pragma unroll
        for (int c = 0; c < 4; c++) {
            o[((size_t)b * 512 + s) * 512 + h * 64 + c * 16 + (lane & 15)] = (bf16_t)(oacc[c][r] * inv);
        }
    }
}

// =====================================================================================
extern "C" void kernel_launch(void* const* d_in, const int* in_sizes, int n_in,
                              void* d_out, int out_size, void* d_ws, size_t ws_size,
                              hipStream_t stream) {
    const float* x_in   = (const float*)d_in[0];
    const float* time_in= (const float*)d_in[1];
    const float* tw1    = (const float*)d_in[2];
    const float* tb1    = (const float*)d_in[3];
    const float* tw2    = (const float*)d_in[4];
    const float* tb2    = (const float*)d_in[5];
    const float* Wq     = (const float*)d_in[6];
    const float* bq     = (const float*)d_in[7];
    const float* Wk     = (const float*)d_in[8];
    const float* bk     = (const float*)d_in[9];
    const float* Wv     = (const float*)d_in[10];
    const float* bv     = (const float*)d_in[11];
    const float* Wo     = (const float*)d_in[12];
    const float* bo     = (const float*)d_in[13];
    const float* attn_g = (const float*)d_in[14];
    const float* attn_b = (const float*)d_in[15];
    const float* ffn_g  = (const float*)d_in[16];
    const float* ffn_b  = (const float*)d_in[17];
    const float* W1     = (const float*)d_in[18];
    const float* b1     = (const float*)d_in[19];
    const float* W2     = (const float*)d_in[20];
    const float* b2     = (const float*)d_in[21];
    const float* Wt     = (const float*)d_in[22];
    const float* bt     = (const float*)d_in[23];
    const float* head_g = (const float*)d_in[24];
    const float* head_b = (const float*)d_in[25];
    const float* Wh     = (const float*)d_in[26];
    const float* bh     = (const float*)d_in[27];

    size_t off = 0;
    auto alloc = [&](size_t bytes) {
        void* r = (char*)d_ws + off;
        off += (bytes + 255) & ~(size_t)255;
        return r;
    };
    bf16_t* wqkv_b = (bf16_t*)alloc((size_t)4 * 3 * 512 * 512 * 2);  // [L][3][512][512]
    bf16_t* wo_b   = (bf16_t*)alloc((size_t)4 * 512 * 512 * 2);
    bf16_t* w1_b   = (bf16_t*)alloc((size_t)4 * 2048 * 512 * 2);
    bf16_t* w2_b   = (bf16_t*)alloc((size_t)4 * 512 * 1024 * 2);
    bf16_t* x_ws   = (bf16_t*)alloc((size_t)16384 * 512 * 2);   // bf16 residual stream
    bf16_t* h_b    = (bf16_t*)alloc((size_t)16384 * 512 * 2);
    bf16_t* q_b    = (bf16_t*)alloc((size_t)16384 * 512 * 2);
    bf16_t* k_b    = (bf16_t*)alloc((size_t)16384 * 512 * 2);
    bf16_t* v_b    = (bf16_t*)alloc((size_t)16384 * 512 * 2);
    bf16_t* o_b    = (bf16_t*)alloc((size_t)16384 * 512 * 2);
    bf16_t* act_b  = (bf16_t*)alloc((size_t)16384 * 1024 * 2);
    float*  temb0  = (float*)alloc((size_t)32 * 512 * 4);
    float*  t1     = (float*)alloc((size_t)32 * 2048 * 4);
    bf16_t* t2s_b  = (bf16_t*)alloc((size_t)32 * 2048 * 2);
    float*  tm_t   = (float*)alloc((size_t)16384 * 32 * 4);
    float*  z      = (float*)alloc((size_t)32 * 512 * 4);

    // weight conversion (every call; deterministic)
    k_f2b_s<<<512, 256, 0, stream>>>(Wq, wqkv_b,          32768, 98304);
    k_f2b_s<<<512, 256, 0, stream>>>(Wk, wqkv_b + 262144, 32768, 98304);
    k_f2b_s<<<512, 256, 0, stream>>>(Wv, wqkv_b + 524288, 32768, 98304);
    k_f2b<<<512, 256, 0, stream>>>(Wo, wo_b, 131072);
    k_f2b<<<2048, 256, 0, stream>>>(W1, w1_b, 524288);
    k_f2b<<<1024, 256, 0, stream>>>(W2, w2_b, 262144);

    // time pipeline
    k_time_embed<<<32, 256, 0, stream>>>(time_in, temb0);
    k_gemm_tm<1, 512, false><<<64, 256, 0, stream>>>(temb0, tw1, tb1, t1, 2048);
    k_gemm_tm<2, 2048, true><<<64, 256, 0, stream>>>(t1, tw2, tb2, t2s_b, 2048);
    k_fill_tmt<<<2048, 256, 0, stream>>>(bt, tm_t);
    k_gemm_wt<<<dim3(256, 4), 256, 0, stream>>>(Wt, t2s_b, tm_t);

    for (int l = 0; l < 4; l++) {
        if (l == 0)
            k_ln<false, true><<<4096, 256, 0, stream>>>(x_in, nullptr, nullptr, h_b);
        else
            k_ln<true, false><<<4096, 256, 0, stream>>>(x_ws, attn_g + l * 512, attn_b + l * 512, h_b);

        k_gemm_wp<EPI_QKV, 512, 12, false><<<1536, 256, 0, stream>>>(
            h_b, wqkv_b + (size_t)l * 786432,
            bq + l * 512, bk + l * 512, bv + l * 512,
            q_b, k_b, v_b, nullptr);

        k_attn<<<2048, 256, 0, stream>>>(q_b, k_b, v_b, o_b);

        if (l == 0)
            k_gemm_wp<EPI_RESID, 512, 4, true><<<512, 256, 0, stream>>>(
                o_b, wo_b + (size_t)l * 262144,
                bo + l * 512, nullptr, nullptr,
                x_ws, x_in, nullptr, nullptr);
        else
            k_gemm_wp<EPI_RESID, 512, 4, false><<<512, 256, 0, stream>>>(
                o_b, wo_b + (size_t)l * 262144,
                bo + l * 512, nullptr, nullptr,
                x_ws, x_ws, nullptr, nullptr);

        k_ln<true, false><<<4096, 256, 0, stream>>>(x_ws, ffn_g + l * 512, ffn_b + l * 512, h_b);

        k_gemm_wp<EPI_FILMGLU, 512, 16, false><<<2048, 256, 0, stream>>>(
            h_b, w1_b + (size_t)l * 1048576,
            b1 + l * 2048, nullptr, nullptr,
            act_b, nullptr, nullptr, tm_t + (size_t)l * 4096 * 32);

        k_gemm_wp<EPI_RESID, 1024, 4, false><<<512, 256, 0, stream>>>(
            act_b, w2_b + (size_t)l * 524288,
            b2 + l * 512, nullptr, nullptr,
            x_ws, x_ws, nullptr, nullptr);
    }

    k_head_prep<<<8, 256, 0, stream>>>(x_ws, head_g, head_b, z);
    k_gemm_tm<0, 512, false><<<16, 256, 0, stream>>>(z, Wh, bh, (float*)d_out, 512);
}

// Round 13
// 1074.683 us; speedup vs baseline: 1.1444x; 1.1444x over previous
//
#include <hip/hip_runtime.h>
#include <math.h>

typedef __bf16 bf16_t;
typedef __bf16 bf16x8 __attribute__((ext_vector_type(8)));
typedef float f32x4 __attribute__((ext_vector_type(4)));

__device__ __forceinline__ void gload_lds16(const void* g, void* l) {
    __builtin_amdgcn_global_load_lds(
        (const __attribute__((address_space(1))) void*)g,
        (__attribute__((address_space(3))) void*)l, 16, 0, 0);
}

// ---------------- f32 -> bf16 convert ----------------
__global__ void k_f2b(const float* __restrict__ in, bf16_t* __restrict__ out, int n8) {
    int idx = blockIdx.x * 256 + threadIdx.x;
    if (idx >= n8) return;
    const float* p = in + (size_t)idx * 8;
    bf16x8 r;
#pragma unroll
    for (int j = 0; j < 8; j++) r[j] = (bf16_t)p[j];
    *(bf16x8*)(out + (size_t)idx * 8) = r;
}

// strided-dest variant (per-layer interleave into wqkv)
__global__ void k_f2b_s(const float* __restrict__ in, bf16_t* __restrict__ out,
                        int seg8, int dstride8) {
    int idx = blockIdx.x * 256 + threadIdx.x;
    int seg = idx / seg8, rem = idx - seg * seg8;
    const float* p = in + (size_t)idx * 8;
    bf16x8 r;
#pragma unroll
    for (int j = 0; j < 8; j++) r[j] = (bf16_t)p[j];
    *(bf16x8*)(out + ((size_t)seg * dstride8 + rem) * 8) = r;
}

// ---------------- sinusoidal time embedding ----------------
__global__ void k_time_embed(const float* __restrict__ time, float* __restrict__ temb0) {
    int b = blockIdx.x;
    int j = threadIdx.x;              // 0..255
    float f = __expf((float)j * -0.036118981458730134f); // -ln(10000)/255
    float e = time[b] * f;
    temb0[(size_t)b * 512 + j] = sinf(e);
    temb0[(size_t)b * 512 + 256 + j] = cosf(e);
}

// ---------------- LayerNorm (or plain cast) -> bf16, rows of 512 ----------------
template<bool DO_NORM, bool IN32>
__global__ void k_ln(const void* __restrict__ xp, const float* __restrict__ g,
                     const float* __restrict__ b, bf16_t* __restrict__ out) {
    int row = blockIdx.x * 4 + (threadIdx.x >> 6);
    int lane = threadIdx.x & 63;
    float vals[8];
    if (IN32) {
        const float* xr = (const float*)xp + (size_t)row * 512 + lane * 8;
        float4 v0 = *(const float4*)xr;
        float4 v1 = *(const float4*)(xr + 4);
        vals[0] = v0.x; vals[1] = v0.y; vals[2] = v0.z; vals[3] = v0.w;
        vals[4] = v1.x; vals[5] = v1.y; vals[6] = v1.z; vals[7] = v1.w;
    } else {
        bf16x8 xv = *(const bf16x8*)((const bf16_t*)xp + (size_t)row * 512 + lane * 8);
#pragma unroll
        for (int j = 0; j < 8; j++) vals[j] = (float)xv[j];
    }
    bf16x8 r;
    if (DO_NORM) {
        float s = 0.f, sq = 0.f;
#pragma unroll
        for (int j = 0; j < 8; j++) { s += vals[j]; sq += vals[j] * vals[j]; }
#pragma unroll
        for (int m = 1; m < 64; m <<= 1) { s += __shfl_xor(s, m, 64); sq += __shfl_xor(sq, m, 64); }
        float mean = s * (1.0f / 512.0f);
        float var = sq * (1.0f / 512.0f) - mean * mean;
        float rstd = rsqrtf(var + 1e-5f);
        float4 g0 = *(const float4*)(g + lane * 8);
        float4 g1 = *(const float4*)(g + lane * 8 + 4);
        float4 b0 = *(const float4*)(b + lane * 8);
        float4 b1 = *(const float4*)(b + lane * 8 + 4);
        float gs[8] = {g0.x, g0.y, g0.z, g0.w, g1.x, g1.y, g1.z, g1.w};
        float bs[8] = {b0.x, b0.y, b0.z, b0.w, b1.x, b1.y, b1.z, b1.w};
#pragma unroll
        for (int j = 0; j < 8; j++) r[j] = (bf16_t)((vals[j] - mean) * rstd * gs[j] + bs[j]);
    } else {
#pragma unroll
        for (int j = 0; j < 8; j++) r[j] = (bf16_t)vals[j];
    }
    *(bf16x8*)(out + (size_t)row * 512 + lane * 8) = r;
}

// ---------------- head prep: LN(x[:, -1]) -> relu -> f32 z[32,512] ----------------
__global__ void k_head_prep(const bf16_t* __restrict__ x, const float* __restrict__ g,
                            const float* __restrict__ b, float* __restrict__ z) {
    int row = blockIdx.x * 4 + (threadIdx.x >> 6); // 0..31
    int lane = threadIdx.x & 63;
    bf16x8 xv = *(const bf16x8*)(x + ((size_t)row * 512 + 511) * 512 + lane * 8);
    float vals[8];
#pragma unroll
    for (int j = 0; j < 8; j++) vals[j] = (float)xv[j];
    float s = 0.f, sq = 0.f;
#pragma unroll
    for (int j = 0; j < 8; j++) { s += vals[j]; sq += vals[j] * vals[j]; }
#pragma unroll
    for (int m = 1; m < 64; m <<= 1) { s += __shfl_xor(s, m, 64); sq += __shfl_xor(sq, m, 64); }
    float mean = s * (1.0f / 512.0f);
    float var = sq * (1.0f / 512.0f) - mean * mean;
    float rstd = rsqrtf(var + 1e-5f);
    float o[8];
#pragma unroll
    for (int j = 0; j < 8; j++) {
        float gv = g[lane * 8 + j], bv = b[lane * 8 + j];
        o[j] = fmaxf((vals[j] - mean) * rstd * gv + bv, 0.0f);
    }
    float* zr = z + (size_t)row * 512 + lane * 8;
    *(float4*)zr = make_float4(o[0], o[1], o[2], o[3]);
    *(float4*)(zr + 4) = make_float4(o[4], o[5], o[6], o[7]);
}

// ---------------- fp32 GEMM, M=32 (time MLP + head) ----------------
template<int ACT, int K, bool OUTB>  // ACT: 0 none, 1 gelu(exact), 2 silu
__global__ __launch_bounds__(256, 2)
void k_gemm_tm(const float* __restrict__ A, const float* __restrict__ W,
               const float* __restrict__ bias, void* __restrict__ outp, int N) {
    __shared__ float Asm[32][516];
    const int t = threadIdx.x;
    const int kq = t & 7, rw = (t >> 3) & 7, bh = t >> 6;
    const int n0 = blockIdx.x * 32;
    float acc[4][8] = {};
    for (int k0 = 0; k0 < K; k0 += 512) {
        __syncthreads();
#pragma unroll
        for (int i = 0; i < 16; i++) {
            int fid = t + i * 256;
            int row = fid >> 7, cc = (fid & 127) << 2;
            *(float4*)&Asm[row][cc] = *(const float4*)&A[(size_t)row * K + k0 + cc];
        }
        __syncthreads();
#pragma unroll 4
        for (int j = 0; j < 16; j++) {
            int kk = kq * 4 + j * 32;
            float4 w4[4];
#pragma unroll
            for (int r = 0; r < 4; r++)
                w4[r] = *(const float4*)&W[(size_t)(n0 + rw + r * 8) * K + k0 + kk];
#pragma unroll
            for (int b = 0; b < 8; b++) {
                float4 a4 = *(const float4*)&Asm[bh * 8 + b][kk];
#pragma unroll
                for (int r = 0; r < 4; r++)
                    acc[r][b] += a4.x * w4[r].x + a4.y * w4[r].y + a4.z * w4[r].z + a4.w * w4[r].w;
            }
        }
    }
#pragma unroll
    for (int m = 1; m < 8; m <<= 1)
#pragma unroll
        for (int r = 0; r < 4; r++)
#pragma unroll
            for (int b = 0; b < 8; b++)
                acc[r][b] += __shfl_xor(acc[r][b], m, 64);
    if (kq == 0) {
#pragma unroll
        for (int r = 0; r < 4; r++) {
            int n = n0 + rw + r * 8;
            float bv = bias[n];
#pragma unroll
            for (int b = 0; b < 8; b++) {
                float v = acc[r][b] + bv;
                if (ACT == 1) v = 0.5f * v * (1.0f + erff(v * 0.70710678118654752f));
                if (ACT == 2) v = v / (1.0f + __expf(-v));
                if (OUTB) ((bf16_t*)outp)[(size_t)(bh * 8 + b) * N + n] = (bf16_t)v;
                else      ((float*)outp)[(size_t)(bh * 8 + b) * N + n] = v;
            }
        }
    }
}

// ---------------- fill [N,32] fp32 with per-row bias ----------------
__global__ void k_fill_tmt(const float* __restrict__ bt, float* __restrict__ dst) {
    int i = blockIdx.x * 256 + threadIdx.x;
    dst[i] = bt[i >> 5];
}

// ---------------- silu + transpose-cast: tmp[2048,32] -> t2s_b[32,2048] bf16 --------
__global__ void k_silu_t(const float* __restrict__ tmp, bf16_t* __restrict__ t2s_b) {
    int i = blockIdx.x * 256 + threadIdx.x;   // over 65536
    float v = tmp[i];
    v = v / (1.0f + __expf(-v));
    int n = i >> 5, b = i & 31;
    t2s_b[(size_t)b * 2048 + n] = (bf16_t)v;
}

// ---------------- split-K GEMM: dst[NR,32] += Wf[NR,2048] @ Bb[32,2048]^T -----------
// A = fp32 weight (converted in-register), B = bf16 [32,2048]; fp32 atomics into dst.
__global__ __launch_bounds__(256, 4)
void k_gemm_wt(const float* __restrict__ Wf, const bf16_t* __restrict__ Bb16,
               float* __restrict__ dst) {
    __shared__ __align__(16) bf16_t Abuf[64 * 64];
    __shared__ __align__(16) bf16_t Bbuf[32 * 64];
    const int tid = threadIdx.x;
    const int m0 = blockIdx.x * 64;
    const int k0 = blockIdx.y * 512;
    const int lane = tid & 63, wave = tid >> 6;
    const int arow = tid >> 2, aseg = tid & 3;
    const int brow = tid >> 3, bseg = tid & 7;
    const int aswz = (arow & 7) << 4;
    const char* Bg = (const char*)Bb16 + (size_t)brow * 4096 + ((bseg * 16) ^ ((brow & 7) << 4));
    char* BbL = (char*)Bbuf + tid * 16;
    const float* Ar0 = Wf + (size_t)(m0 + arow) * 2048 + k0 + aseg * 16;
    f32x4 acc[2] = {};
    for (int kk0 = 0; kk0 < 512; kk0 += 64) {
        float4 a4[4];
#pragma unroll
        for (int i = 0; i < 4; i++) a4[i] = *(const float4*)(Ar0 + kk0 + i * 4);
        __syncthreads();
        gload_lds16(Bg + (size_t)(k0 + kk0) * 2, BbL);
        bf16x8 c0, c1;
#pragma unroll
        for (int i = 0; i < 4; i++) {
            const float* af = (const float*)&a4[i];
#pragma unroll
            for (int j = 0; j < 4; j++) {
                if (i < 2) c0[i * 4 + j] = (bf16_t)af[j];
                else       c1[(i - 2) * 4 + j] = (bf16_t)af[j];
            }
        }
        int base = arow * 128 + aseg * 32;
        *(bf16x8*)((char*)Abuf + (base ^ aswz)) = c0;
        *(bf16x8*)((char*)Abuf + ((base + 16) ^ aswz)) = c1;
        __syncthreads();
#pragma unroll
        for (int kk = 0; kk < 2; kk++) {
            int ar = wave * 16 + (lane & 15);
            bf16x8 af = *(const bf16x8*)((const char*)Abuf + ar * 128 +
                        ((kk * 64 + (lane >> 4) * 16) ^ ((ar & 7) << 4)));
#pragma unroll
            for (int j = 0; j < 2; j++) {
                int br = j * 16 + (lane & 15);
                bf16x8 bfr = *(const bf16x8*)((const char*)Bbuf + br * 128 +
                             ((kk * 64 + (lane >> 4) * 16) ^ ((br & 7) << 4)));
                acc[j] = __builtin_amdgcn_mfma_f32_16x16x32_bf16(af, bfr, acc[j], 0, 0, 0);
            }
        }
    }
#pragma unroll
    for (int j = 0; j < 2; j++)
#pragma unroll
        for (int r = 0; r < 4; r++) {
            int mrow = m0 + wave * 16 + (lane >> 4) * 4 + r;
            atomicAdd(&dst[(size_t)mrow * 32 + j * 16 + (lane & 15)], acc[j][r]);
        }
}

// ---------------- MFMA GEMM (R4 structure: single-buffer, 4 blocks/CU) ----------------
enum { EPI_QKV = 0, EPI_RESID = 1, EPI_FILMGLU = 2 };

template<int EPI, int K, int NBY, int BM, bool RS32>
__global__ __launch_bounds__(BM * 2, 4)
void k_gemm_bt(const bf16_t* __restrict__ A, const bf16_t* __restrict__ W,
               const float* __restrict__ bias, const float* __restrict__ bias2,
               const float* __restrict__ bias3,
               void* __restrict__ out0, const void* __restrict__ rsp, void* __restrict__ out2,
               const float* __restrict__ tm) {
    constexpr int T   = BM * 2;
    constexpr int RPR = BM / 4;
    constexpr int BR  = 512 / BM;
    __shared__ __align__(16) bf16_t Abuf[BM * 64];
    __shared__ __align__(16) bf16_t Bbuf[128 * 64];
    const int tid = threadIdx.x;
    const int cpx = gridDim.x >> 3;
    const int wg = (blockIdx.x & 7) * cpx + (blockIdx.x >> 3);
    const int bx = wg / NBY;
    const int by = wg - bx * NBY;
    const int m0 = bx * BM;
    const int lane = tid & 63;
    const int wid = tid >> 6;
    const int wrM = (wid >> 1) * 64;
    const int wN  = wid & 1;
    const int wc  = wN * 64;

    const int srow = tid >> 3;
    const int goff = ((tid & 7) * 16) ^ ((srow & 7) << 4);
    const char* Ag = (const char*)A;
    const char* Wg = (const char*)W;
    char* AbL = (char*)Abuf + tid * 16;
    char* BbL = (char*)Bbuf + tid * 16;
    int growB[BR];
#pragma unroll
    for (int i = 0; i < BR; i++) {
        int r = srow + i * RPR;
        if (EPI == EPI_FILMGLU) {
            int half = (r >> 5) & 1;
            int base = by * 64 + (r >> 6) * 32 + (r & 31);
            growB[i] = half * 1024 + base;
        } else {
            growB[i] = by * 128 + r;
        }
    }

    f32x4 acc[4][4] = {};
    for (int k0 = 0; k0 < K * 2; k0 += 128) {
        __syncthreads();
#pragma unroll
        for (int i = 0; i < 4; i++)
            gload_lds16(Ag + (size_t)(m0 + srow + i * RPR) * (K * 2) + k0 + goff, AbL + i * (T * 16));
#pragma unroll
        for (int i = 0; i < BR; i++)
            gload_lds16(Wg + (size_t)growB[i] * (K * 2) + k0 + goff, BbL + i * (T * 16));
        __syncthreads();
#pragma unroll
        for (int kk = 0; kk < 2; kk++) {
            bf16x8 af[4], bfr[4];
#pragma unroll
            for (int i = 0; i < 4; i++) {
                int ar = wrM + i * 16 + (lane & 15);
                af[i] = *(const bf16x8*)((const char*)Abuf + ar * 128 +
                         ((kk * 64 + (lane >> 4) * 16) ^ ((ar & 7) << 4)));
                int br = wc + i * 16 + (lane & 15);
                bfr[i] = *(const bf16x8*)((const char*)Bbuf + br * 128 +
                         ((kk * 64 + (lane >> 4) * 16) ^ ((br & 7) << 4)));
            }
#pragma unroll
            for (int i = 0; i < 4; i++)
#pragma unroll
                for (int j = 0; j < 4; j++)
                    acc[i][j] = __builtin_amdgcn_mfma_f32_16x16x32_bf16(af[i], bfr[j], acc[i][j], 0, 0, 0);
        }
    }

    const int b = m0 >> 9;
    if (EPI == EPI_QKV) {
        const int which = by >> 2;
        bf16_t* op = (bf16_t*)(which == 0 ? out0 : which == 1 ? (void*)rsp : out2);
        const float* bp = which == 0 ? bias : which == 1 ? bias2 : bias3;
#pragma unroll
        for (int i = 0; i < 4; i++) {
#pragma unroll
            for (int r = 0; r < 4; r++) {
                int s = (m0 + wrM + i * 16 + (lane >> 4) * 4 + r) & 511;
#pragma unroll
                for (int j = 0; j < 4; j++) {
                    int c = (by & 3) * 128 + wc + j * 16 + (lane & 15);
                    float v = acc[i][j][r] + bp[c];
                    int h = c >> 6, dh = c & 63;
                    op[(((size_t)b * 8 + h) * 512 + s) * 64 + dh] = (bf16_t)v;
                }
            }
        }
    } else if (EPI == EPI_RESID) {
        bf16_t* op = (bf16_t*)out0;
#pragma unroll
        for (int i = 0; i < 4; i++) {
#pragma unroll
            for (int r = 0; r < 4; r++) {
                int row = m0 + wrM + i * 16 + (lane >> 4) * 4 + r;
#pragma unroll
                for (int j = 0; j < 4; j++) {
                    int col = by * 128 + wc + j * 16 + (lane & 15);
                    size_t idx = (size_t)row * 512 + col;
                    float rsv = RS32 ? ((const float*)rsp)[idx] : (float)((const bf16_t*)rsp)[idx];
                    op[idx] = (bf16_t)(rsv + acc[i][j][r] + bias[col]);
                }
            }
        }
    } else { // EPI_FILMGLU; tm is tm_t layout [16384 cols][32 batches]
        bf16_t* op = (bf16_t*)out0;
#pragma unroll
        for (int i = 0; i < 4; i++) {
#pragma unroll
            for (int r = 0; r < 4; r++) {
                int row = m0 + wrM + i * 16 + (lane >> 4) * 4 + r;
#pragma unroll
                for (int jj = 0; jj < 2; jj++) {
                    int colA = by * 64 + wN * 32 + jj * 16 + (lane & 15);
                    float av = acc[i][jj][r] + bias[colA];
                    float gv = acc[i][jj + 2][r] + bias[1024 + colA];
                    float sa = tm[(size_t)colA * 32 + b];
                    float ha = tm[(size_t)(2048 + colA) * 32 + b];
                    float sg = tm[(size_t)(1024 + colA) * 32 + b];
                    float hg = tm[(size_t)(3072 + colA) * 32 + b];
                    av = av * (1.0f + sa) + ha;
                    gv = gv * (1.0f + sg) + hg;
                    op[(size_t)row * 1024 + colA] = (bf16_t)(av * fmaxf(gv, 0.0f));
                }
            }
        }
    }
}

// ---------------- fused flash attention: 128 q-rows (2 tiles) per block --------------
__global__ __launch_bounds__(256, 2)
void k_attn(const bf16_t* __restrict__ q, const bf16_t* __restrict__ k,
            const bf16_t* __restrict__ v, bf16_t* __restrict__ o) {
    __shared__ bf16_t q_lds[2][64][72];
    __shared__ bf16_t k_lds[64][72];
    __shared__ bf16_t vt_lds[64 * 72];   // row d (stride 144B), cols s, XOR-swizzled
    __shared__ bf16_t p_lds[64][72];
    const int tid = threadIdx.x;
    const int lane = tid & 63;
    const int wave = tid >> 6;
    // XCD swizzle: the 4 blocks of one (b,h) land on one XCD for K/V L2 reuse
    const int cpx = gridDim.x >> 3;                              // 128
    const int wg = ((int)blockIdx.x & 7) * cpx + ((int)blockIdx.x >> 3);
    const int bh = wg >> 2;      // 0..255
    const int qt2 = wg & 3;      // 0..3 (128 q-rows each)
    const bf16_t* kb = k + (size_t)bh * 512 * 64;
    const bf16_t* vb = v + (size_t)bh * 512 * 64;
    const int sr = tid >> 2;          // 0..63
    const int sc = (tid & 3) * 16;    // 0,16,32,48
#pragma unroll
    for (int qi = 0; qi < 2; qi++) {  // stage both Q tiles, folding SCALE=0.125
        const bf16_t* qb = q + ((size_t)bh * 512 + qt2 * 128 + qi * 64) * 64;
        bf16x8 a0 = *(const bf16x8*)(qb + sr * 64 + sc);
        bf16x8 a1 = *(const bf16x8*)(qb + sr * 64 + sc + 8);
        bf16x8 ra, rb;
#pragma unroll
        for (int j = 0; j < 8; j++) {
            ra[j] = (bf16_t)((float)a0[j] * 0.125f);
            rb[j] = (bf16_t)((float)a1[j] * 0.125f);
        }
        *(bf16x8*)&q_lds[qi][sr][sc] = ra;
        *(bf16x8*)&q_lds[qi][sr][sc + 8] = rb;
    }
    // prefetch regs for K/V tile 0
    bf16x8 kr0, kr1, vr0, vr1;
    {
        const bf16_t* ks = kb + (size_t)sr * 64 + sc;
        const bf16_t* vs = vb + (size_t)sr * 64 + sc;
        kr0 = *(const bf16x8*)ks; kr1 = *(const bf16x8*)(ks + 8);
        vr0 = *(const bf16x8*)vs; vr1 = *(const bf16x8*)(vs + 8);
    }
    float mrow[2][4], lrow[2][4];
    f32x4 oacc[2][4] = {};
#pragma unroll
    for (int qi = 0; qi < 2; qi++)
#pragma unroll
        for (int r = 0; r < 4; r++) { mrow[qi][r] = -1e30f; lrow[qi][r] = 0.f; }
    const int swz0 = ((sc >> 3) & 7) << 4;
    const int swz1 = (((sc + 8) >> 3) & 7) << 4;
    for (int kt = 0; kt < 8; kt++) {
        __syncthreads();
        {
            *(bf16x8*)&k_lds[sr][sc] = kr0;
            *(bf16x8*)&k_lds[sr][sc + 8] = kr1;
            char* vbase = (char*)vt_lds;
            int so0 = (sr * 2) ^ swz0;
            int so1 = (sr * 2) ^ swz1;
#pragma unroll
            for (int j = 0; j < 8; j++) {
                *(bf16_t*)(vbase + (sc + j) * 144 + so0) = vr0[j];
                *(bf16_t*)(vbase + (sc + 8 + j) * 144 + so1) = vr1[j];
            }
        }
        __syncthreads();
        if (kt < 7) {
            const bf16_t* ks = kb + ((size_t)(kt + 1) * 64 + sr) * 64 + sc;
            const bf16_t* vs = vb + ((size_t)(kt + 1) * 64 + sr) * 64 + sc;
            kr0 = *(const bf16x8*)ks; kr1 = *(const bf16x8*)(ks + 8);
            vr0 = *(const bf16x8*)vs; vr1 = *(const bf16x8*)(vs + 8);
        }
#pragma unroll
        for (int qi = 0; qi < 2; qi++) {
            f32x4 sacc[4] = {};
#pragma unroll
            for (int kk = 0; kk < 2; kk++) {
                bf16x8 aq = *(const bf16x8*)&q_lds[qi][wave * 16 + (lane & 15)][kk * 32 + (lane >> 4) * 8];
#pragma unroll
                for (int c = 0; c < 4; c++) {
                    bf16x8 bk8 = *(const bf16x8*)&k_lds[c * 16 + (lane & 15)][kk * 32 + (lane >> 4) * 8];
                    sacc[c] = __builtin_amdgcn_mfma_f32_16x16x32_bf16(aq, bk8, sacc[c], 0, 0, 0);
                }
            }
#pragma unroll
            for (int r = 0; r < 4; r++) {
                float mx = fmaxf(fmaxf(sacc[0][r], sacc[1][r]), fmaxf(sacc[2][r], sacc[3][r]));
#pragma unroll
                for (int m = 1; m < 16; m <<= 1) mx = fmaxf(mx, __shfl_xor(mx, m, 64));
                float newm = fmaxf(mrow[qi][r], mx);
                float fsc = __expf(mrow[qi][r] - newm);
                mrow[qi][r] = newm;
                float p0 = __expf(sacc[0][r] - newm);
                float p1 = __expf(sacc[1][r] - newm);
                float p2 = __expf(sacc[2][r] - newm);
                float p3 = __expf(sacc[3][r] - newm);
                float ps = p0 + p1 + p2 + p3;
#pragma unroll
                for (int m = 1; m < 16; m <<= 1) ps += __shfl_xor(ps, m, 64);
                lrow[qi][r] = lrow[qi][r] * fsc + ps;
#pragma unroll
                for (int c = 0; c < 4; c++) oacc[qi][c][r] *= fsc;
                int qrow = wave * 16 + (lane >> 4) * 4 + r;
                p_lds[qrow][(lane & 15)] = (bf16_t)p0;
                p_lds[qrow][16 + (lane & 15)] = (bf16_t)p1;
                p_lds[qrow][32 + (lane & 15)] = (bf16_t)p2;
                p_lds[qrow][48 + (lane & 15)] = (bf16_t)p3;
            }
            // p_lds is wave-local; same-wave DS ops complete in order -> safe reuse
#pragma unroll
            for (int kk = 0; kk < 2; kk++) {
                bf16x8 ap = *(const bf16x8*)&p_lds[wave * 16 + (lane & 15)][kk * 32 + (lane >> 4) * 8];
#pragma unroll
                for (int c = 0; c < 4; c++) {
                    int d0 = c * 16 + (lane & 15);
                    int xo = ((d0 >> 3) & 7) << 4;
                    bf16x8 bv8 = *(const bf16x8*)((const char*)vt_lds + d0 * 144 +
                                  ((kk * 64 + (lane >> 4) * 16) ^ xo));
                    oacc[qi][c] = __builtin_amdgcn_mfma_f32_16x16x32_bf16(ap, bv8, oacc[qi][c], 0, 0, 0);
                }
            }
        }
    }
    const int b = bh >> 3, h = bh & 7;
#pragma unroll
    for (int qi = 0; qi < 2; qi++) {
#pragma unroll
        for (int r = 0; r < 4; r++) {
            int s = qt2 * 128 + qi * 64 + wave * 16 + (lane >> 4) * 4 + r;
            float inv = 1.0f / lrow[qi][r];
#pragma unroll
            for (int c = 0; c < 4; c++) {
                o[((size_t)b * 512 + s) * 512 + h * 64 + c * 16 + (lane & 15)] = (bf16_t)(oacc[qi][c][r] * inv);
            }
        }
    }
}

// =====================================================================================
extern "C" void kernel_launch(void* const* d_in, const int* in_sizes, int n_in,
                              void* d_out, int out_size, void* d_ws, size_t ws_size,
                              hipStream_t stream) {
    const float* x_in   = (const float*)d_in[0];
    const float* time_in= (const float*)d_in[1];
    const float* tw1    = (const float*)d_in[2];
    const float* tb1    = (const float*)d_in[3];
    const float* tw2    = (const float*)d_in[4];
    const float* tb2    = (const float*)d_in[5];
    const float* Wq     = (const float*)d_in[6];
    const float* bq     = (const float*)d_in[7];
    const float* Wk     = (const float*)d_in[8];
    const float* bk     = (const float*)d_in[9];
    const float* Wv     = (const float*)d_in[10];
    const float* bv     = (const float*)d_in[11];
    const float* Wo     = (const float*)d_in[12];
    const float* bo     = (const float*)d_in[13];
    const float* attn_g = (const float*)d_in[14];
    const float* attn_b = (const float*)d_in[15];
    const float* ffn_g  = (const float*)d_in[16];
    const float* ffn_b  = (const float*)d_in[17];
    const float* W1     = (const float*)d_in[18];
    const float* b1     = (const float*)d_in[19];
    const float* W2     = (const float*)d_in[20];
    const float* b2     = (const float*)d_in[21];
    const float* Wt     = (const float*)d_in[22];
    const float* bt     = (const float*)d_in[23];
    const float* head_g = (const float*)d_in[24];
    const float* head_b = (const float*)d_in[25];
    const float* Wh     = (const float*)d_in[26];
    const float* bh     = (const float*)d_in[27];

    size_t off = 0;
    auto alloc = [&](size_t bytes) {
        void* r = (char*)d_ws + off;
        off += (bytes + 255) & ~(size_t)255;
        return r;
    };
    bf16_t* wqkv_b = (bf16_t*)alloc((size_t)4 * 3 * 512 * 512 * 2);  // [L][3][512][512]
    bf16_t* wo_b   = (bf16_t*)alloc((size_t)4 * 512 * 512 * 2);
    bf16_t* w1_b   = (bf16_t*)alloc((size_t)4 * 2048 * 512 * 2);
    bf16_t* w2_b   = (bf16_t*)alloc((size_t)4 * 512 * 1024 * 2);
    bf16_t* x_ws   = (bf16_t*)alloc((size_t)16384 * 512 * 2);   // bf16 residual stream
    bf16_t* h_b    = (bf16_t*)alloc((size_t)16384 * 512 * 2);
    bf16_t* q_b    = (bf16_t*)alloc((size_t)16384 * 512 * 2);
    bf16_t* k_b    = (bf16_t*)alloc((size_t)16384 * 512 * 2);
    bf16_t* v_b    = (bf16_t*)alloc((size_t)16384 * 512 * 2);
    bf16_t* o_b    = (bf16_t*)alloc((size_t)16384 * 512 * 2);
    bf16_t* act_b  = (bf16_t*)alloc((size_t)16384 * 1024 * 2);
    float*  temb0  = (float*)alloc((size_t)32 * 512 * 4);
    bf16_t* t1_b   = (bf16_t*)alloc((size_t)32 * 2048 * 2);
    float*  tmp2   = (float*)alloc((size_t)2048 * 32 * 4);
    bf16_t* t2s_b  = (bf16_t*)alloc((size_t)32 * 2048 * 2);
    float*  tm_t   = (float*)alloc((size_t)16384 * 32 * 4);
    float*  z      = (float*)alloc((size_t)32 * 512 * 4);

    // weight conversion (every call; deterministic)
    k_f2b_s<<<512, 256, 0, stream>>>(Wq, wqkv_b,          32768, 98304);
    k_f2b_s<<<512, 256, 0, stream>>>(Wk, wqkv_b + 262144, 32768, 98304);
    k_f2b_s<<<512, 256, 0, stream>>>(Wv, wqkv_b + 524288, 32768, 98304);
    k_f2b<<<512, 256, 0, stream>>>(Wo, wo_b, 131072);
    k_f2b<<<2048, 256, 0, stream>>>(W1, w1_b, 524288);
    k_f2b<<<1024, 256, 0, stream>>>(W2, w2_b, 262144);

    // time pipeline
    k_time_embed<<<32, 256, 0, stream>>>(time_in, temb0);
    k_gemm_tm<1, 512, true><<<64, 256, 0, stream>>>(temb0, tw1, tb1, t1_b, 2048);
    k_fill_tmt<<<256, 256, 0, stream>>>(tb2, tmp2);
    k_gemm_wt<<<dim3(32, 4), 256, 0, stream>>>(tw2, t1_b, tmp2);
    k_silu_t<<<256, 256, 0, stream>>>(tmp2, t2s_b);
    k_fill_tmt<<<2048, 256, 0, stream>>>(bt, tm_t);
    k_gemm_wt<<<dim3(256, 4), 256, 0, stream>>>(Wt, t2s_b, tm_t);

    for (int l = 0; l < 4; l++) {
        if (l == 0)
            k_ln<false, true><<<4096, 256, 0, stream>>>(x_in, nullptr, nullptr, h_b);
        else
            k_ln<true, false><<<4096, 256, 0, stream>>>(x_ws, attn_g + l * 512, attn_b + l * 512, h_b);

        k_gemm_bt<EPI_QKV, 512, 12, 128, false><<<1536, 256, 0, stream>>>(
            h_b, wqkv_b + (size_t)l * 786432,
            bq + l * 512, bk + l * 512, bv + l * 512,
            q_b, k_b, v_b, nullptr);

        k_attn<<<1024, 256, 0, stream>>>(q_b, k_b, v_b, o_b);

        if (l == 0)
            k_gemm_bt<EPI_RESID, 512, 4, 128, true><<<512, 256, 0, stream>>>(
                o_b, wo_b + (size_t)l * 262144,
                bo + l * 512, nullptr, nullptr,
                x_ws, x_in, nullptr, nullptr);
        else
            k_gemm_bt<EPI_RESID, 512, 4, 128, false><<<512, 256, 0, stream>>>(
                o_b, wo_b + (size_t)l * 262144,
                bo + l * 512, nullptr, nullptr,
                x_ws, x_ws, nullptr, nullptr);

        k_ln<true, false><<<4096, 256, 0, stream>>>(x_ws, ffn_g + l * 512, ffn_b + l * 512, h_b);

        k_gemm_bt<EPI_FILMGLU, 512, 16, 128, false><<<2048, 256, 0, stream>>>(
            h_b, w1_b + (size_t)l * 1048576,
            b1 + l * 2048, nullptr, nullptr,
            act_b, nullptr, nullptr, tm_t + (size_t)l * 4096 * 32);

        k_gemm_bt<EPI_RESID, 1024, 4, 128, false><<<512, 256, 0, stream>>>(
            act_b, w2_b + (size_t)l * 524288,
            b2 + l * 512, nullptr, nullptr,
            x_ws, x_ws, nullptr, nullptr);
    }

    k_head_prep<<<8, 256, 0, stream>>>(x_ws, head_g, head_b, z);
    k_gemm_tm<0, 512, false><<<16, 256, 0, stream>>>(z, Wh, bh, (float*)d_out, 512);
}